// Round 1
// baseline (2104.804 us; speedup 1.0000x reference)
//
#include <hip/hip_runtime.h>
#include <math.h>

#define NN 20000
#define EE 320000
#define ETOT 340000

__device__ __forceinline__ float lrelu(float x, float s) { return x > 0.f ? x : s * x; }

// ---------------- CSR build ----------------
__global__ void k_count(const int* __restrict__ ei, int* __restrict__ counts) {
    int i = blockIdx.x * blockDim.x + threadIdx.x;
    if (i >= ETOT) return;
    int d = (i < EE) ? ei[EE + i] : (i - EE);
    atomicAdd(&counts[d], 1);
}

__global__ __launch_bounds__(1024) void k_scan(const int* __restrict__ counts, int* __restrict__ rstart) {
    __shared__ int sm[1024];
    int t = threadIdx.x;
    const int CH = 20;  // 1024*20 = 20480 >= NN
    int base = t * CH;
    int loc[CH];
    int s = 0;
#pragma unroll
    for (int j = 0; j < CH; ++j) {
        int idx = base + j;
        int v = (idx < NN) ? counts[idx] : 0;
        loc[j] = s;
        s += v;
    }
    sm[t] = s;
    __syncthreads();
    for (int o = 1; o < 1024; o <<= 1) {
        int v = (t >= o) ? sm[t - o] : 0;
        __syncthreads();
        if (t >= o) sm[t] += v;
        __syncthreads();
    }
    int off = sm[t] - s;  // exclusive prefix
#pragma unroll
    for (int j = 0; j < CH; ++j) {
        int idx = base + j;
        if (idx < NN) rstart[idx] = off + loc[j];
    }
    if (t == 1023) rstart[NN] = sm[1023];
}

__global__ void k_scatter(const int* __restrict__ ei, const int* __restrict__ rstart,
                          int* __restrict__ cursor, int* __restrict__ csr) {
    int i = blockIdx.x * blockDim.x + threadIdx.x;
    if (i >= ETOT) return;
    int d = (i < EE) ? ei[EE + i] : (i - EE);
    int pos = atomicAdd(&cursor[d], 1);
    csr[rstart[d] + pos] = i;
}

// ---------------- GEMM: C[M x 512] = A[M x 512] @ W[512 x 512]^T + bias ----------------
#define BM 128
#define BN 128
#define BK 16
__global__ __launch_bounds__(256) void k_gemm(const float* __restrict__ A, const float* __restrict__ W,
                                              const float* __restrict__ bias, float* __restrict__ Cout, int M) {
    __shared__ float As[BK][BM + 4];
    __shared__ float Bs[BK][BN + 4];
    int tid = threadIdx.x;
    int bm = blockIdx.x * BM;
    int bn = blockIdx.y * BN;
    int tx = tid & 15, ty = tid >> 4;
    int lr = tid >> 2;           // 0..63
    int lk = (tid & 3) << 2;     // 0,4,8,12
    float acc[8][8] = {};
    for (int k0 = 0; k0 < 512; k0 += BK) {
#pragma unroll
        for (int half = 0; half < 2; ++half) {
            int r = lr + half * 64;
            int gr = bm + r;
            float4 v = (gr < M) ? *(const float4*)(A + (size_t)gr * 512 + k0 + lk) : make_float4(0.f, 0.f, 0.f, 0.f);
            As[lk + 0][r] = v.x; As[lk + 1][r] = v.y; As[lk + 2][r] = v.z; As[lk + 3][r] = v.w;
        }
#pragma unroll
        for (int half = 0; half < 2; ++half) {
            int r = lr + half * 64;
            float4 v = *(const float4*)(W + (size_t)(bn + r) * 512 + k0 + lk);
            Bs[lk + 0][r] = v.x; Bs[lk + 1][r] = v.y; Bs[lk + 2][r] = v.z; Bs[lk + 3][r] = v.w;
        }
        __syncthreads();
#pragma unroll
        for (int k = 0; k < BK; ++k) {
            float a[8], b[8];
#pragma unroll
            for (int i = 0; i < 8; ++i) a[i] = As[k][ty * 8 + i];
#pragma unroll
            for (int j = 0; j < 8; ++j) b[j] = Bs[k][tx * 8 + j];
#pragma unroll
            for (int i = 0; i < 8; ++i)
#pragma unroll
                for (int j = 0; j < 8; ++j) acc[i][j] += a[i] * b[j];
        }
        __syncthreads();
    }
#pragma unroll
    for (int i = 0; i < 8; ++i) {
        int gr = bm + ty * 8 + i;
        if (gr >= M) continue;
#pragma unroll
        for (int j = 0; j < 8; j += 4) {
            int gc = bn + tx * 8 + j;
            float4 v;
            v.x = acc[i][j + 0] + bias[gc + 0];
            v.y = acc[i][j + 1] + bias[gc + 1];
            v.z = acc[i][j + 2] + bias[gc + 2];
            v.w = acc[i][j + 3] + bias[gc + 3];
            *(float4*)(Cout + (size_t)gr * 512 + gc) = v;
        }
    }
}

// ---------------- edge logits: one wave per edge ----------------
__global__ __launch_bounds__(256) void k_logits(const float* __restrict__ xl, const float* __restrict__ xr,
                                                const float* __restrict__ att, const int* __restrict__ ei,
                                                float* __restrict__ lg) {
    int gid = blockIdx.x * 4 + (threadIdx.x >> 6);
    int lane = threadIdx.x & 63;
    if (gid >= ETOT) return;
    int s = (gid < EE) ? ei[gid] : gid - EE;
    int d = (gid < EE) ? ei[EE + gid] : gid - EE;
    const float4* ls = (const float4*)(xl + (size_t)s * 512) + lane * 2;
    const float4* rd = (const float4*)(xr + (size_t)d * 512) + lane * 2;
    const float4* at = (const float4*)att + lane * 2;
    float p = 0.f;
#pragma unroll
    for (int q = 0; q < 2; ++q) {
        float4 a = ls[q], b = rd[q], w = at[q];
        float ex = lrelu(a.x + b.x, 0.2f);
        float ey = lrelu(a.y + b.y, 0.2f);
        float ez = lrelu(a.z + b.z, 0.2f);
        float ew = lrelu(a.w + b.w, 0.2f);
        p += ex * w.x + ey * w.y + ez * w.z + ew * w.w;
    }
    p += __shfl_xor(p, 1);
    p += __shfl_xor(p, 2);
    p += __shfl_xor(p, 4);
    p += __shfl_xor(p, 8);
    if ((lane & 15) == 0) lg[(size_t)gid * 4 + (lane >> 4)] = p;
}

// ---------------- per-dst softmax over CSR row: one wave per node ----------------
__global__ __launch_bounds__(256) void k_softmax(const float* __restrict__ lg, const int* __restrict__ rstart,
                                                 const int* __restrict__ csr, float* __restrict__ alpha) {
    int node = blockIdx.x * 4 + (threadIdx.x >> 6);
    int lane = threadIdx.x & 63;
    if (node >= NN) return;
    int s0 = rstart[node];
    int deg = rstart[node + 1] - s0;
    float m0 = -1e30f, m1 = -1e30f, m2 = -1e30f, m3 = -1e30f;
    for (int i = lane; i < deg; i += 64) {
        const float4 l = *(const float4*)(lg + (size_t)csr[s0 + i] * 4);
        m0 = fmaxf(m0, l.x); m1 = fmaxf(m1, l.y); m2 = fmaxf(m2, l.z); m3 = fmaxf(m3, l.w);
    }
#pragma unroll
    for (int o = 32; o >= 1; o >>= 1) {
        m0 = fmaxf(m0, __shfl_xor(m0, o));
        m1 = fmaxf(m1, __shfl_xor(m1, o));
        m2 = fmaxf(m2, __shfl_xor(m2, o));
        m3 = fmaxf(m3, __shfl_xor(m3, o));
    }
    float t0 = 0.f, t1 = 0.f, t2 = 0.f, t3 = 0.f;
    for (int i = lane; i < deg; i += 64) {
        const float4 l = *(const float4*)(lg + (size_t)csr[s0 + i] * 4);
        t0 += expf(l.x - m0); t1 += expf(l.y - m1); t2 += expf(l.z - m2); t3 += expf(l.w - m3);
    }
#pragma unroll
    for (int o = 32; o >= 1; o >>= 1) {
        t0 += __shfl_xor(t0, o); t1 += __shfl_xor(t1, o); t2 += __shfl_xor(t2, o); t3 += __shfl_xor(t3, o);
    }
    float r0 = 1.f / t0, r1 = 1.f / t1, r2 = 1.f / t2, r3 = 1.f / t3;
    for (int i = lane; i < deg; i += 64) {
        int e = csr[s0 + i];
        const float4 l = *(const float4*)(lg + (size_t)e * 4);
        float4 a;
        a.x = expf(l.x - m0) * r0;
        a.y = expf(l.y - m1) * r1;
        a.z = expf(l.z - m2) * r2;
        a.w = expf(l.w - m3) * r3;
        *(float4*)(alpha + (size_t)e * 4) = a;
    }
}

// ---------------- aggregate: one wave per node, 8 channels/lane in regs ----------------
__global__ __launch_bounds__(256) void k_agg(const float* __restrict__ xl, const float* __restrict__ alpha,
                                             const int* __restrict__ ei, const int* __restrict__ rstart,
                                             const int* __restrict__ csr, const float* __restrict__ bias,
                                             float* __restrict__ out, int meanHeads) {
    int node = blockIdx.x * 4 + (threadIdx.x >> 6);
    int lane = threadIdx.x & 63;
    if (node >= NN) return;
    int s0 = rstart[node];
    int deg = rstart[node + 1] - s0;
    int hh = lane >> 4;
    float4 a0 = {0.f, 0.f, 0.f, 0.f}, a1 = {0.f, 0.f, 0.f, 0.f};
    for (int i = 0; i < deg; ++i) {
        int e = csr[s0 + i];
        int s = (e < EE) ? ei[e] : e - EE;
        float al = alpha[(size_t)e * 4 + hh];
        const float4* row = (const float4*)(xl + (size_t)s * 512) + lane * 2;
        float4 r0 = row[0], r1 = row[1];
        a0.x += al * r0.x; a0.y += al * r0.y; a0.z += al * r0.z; a0.w += al * r0.w;
        a1.x += al * r1.x; a1.y += al * r1.y; a1.z += al * r1.z; a1.w += al * r1.w;
    }
    if (!meanHeads) {
        const float4* bb = (const float4*)bias + lane * 2;
        float4 b0 = bb[0], b1 = bb[1];
        float4 w0, w1;
        w0.x = a0.x + b0.x; w0.y = a0.y + b0.y; w0.z = a0.z + b0.z; w0.w = a0.w + b0.w;
        w1.x = a1.x + b1.x; w1.y = a1.y + b1.y; w1.z = a1.z + b1.z; w1.w = a1.w + b1.w;
        float4* o = (float4*)(out + (size_t)node * 512) + lane * 2;
        o[0] = w0;
        o[1] = w1;
    } else {
        float v[8] = {a0.x, a0.y, a0.z, a0.w, a1.x, a1.y, a1.z, a1.w};
#pragma unroll
        for (int j = 0; j < 8; ++j) {
            v[j] += __shfl_xor(v[j], 16);
            v[j] += __shfl_xor(v[j], 32);
        }
        if (lane < 16) {
            int c = lane * 8;
#pragma unroll
            for (int j = 0; j < 8; ++j) out[(size_t)node * 128 + c + j] = 0.25f * v[j] + bias[c + j];
        }
    }
}

// ---------------- batch norm ----------------
__global__ void k_bnstats(const float* __restrict__ X, float* __restrict__ s, float* __restrict__ s2, int ncols) {
    int col = threadIdx.x;
    float a = 0.f, q = 0.f;
    for (int r = blockIdx.x; r < NN; r += gridDim.x) {
        float v = X[(size_t)r * ncols + col];
        a += v;
        q += v * v;
    }
    atomicAdd(&s[col], a);
    atomicAdd(&s2[col], q);
}

__global__ void k_bnfin(const float* __restrict__ s, const float* __restrict__ s2, float* __restrict__ mu,
                        float* __restrict__ rs, int ncols) {
    int c = threadIdx.x;
    if (c < ncols) {
        float m = s[c] * (1.f / NN);
        float v = s2[c] * (1.f / NN) - m * m;
        mu[c] = m;
        rs[c] = rsqrtf(v + 1e-5f);
    }
}

__global__ void k_bnapply(const float* __restrict__ X, const float* __restrict__ g, const float* __restrict__ b,
                          const float* __restrict__ mu, const float* __restrict__ rs, float* __restrict__ Y,
                          int mask4, int n4) {
    int i = blockIdx.x * blockDim.x + threadIdx.x;
    if (i >= n4) return;
    int c = (i & mask4) << 2;
    float4 x = ((const float4*)X)[i];
    float4 G = *(const float4*)(g + c);
    float4 B = *(const float4*)(b + c);
    float4 M = *(const float4*)(mu + c);
    float4 R = *(const float4*)(rs + c);
    float4 y;
    y.x = lrelu(G.x * (x.x - M.x) * R.x + B.x, 0.01f);
    y.y = lrelu(G.y * (x.y - M.y) * R.y + B.y, 0.01f);
    y.z = lrelu(G.z * (x.z - M.z) * R.z + B.z, 0.01f);
    y.w = lrelu(G.w * (x.w - M.w) * R.w + B.w, 0.01f);
    ((float4*)Y)[i] = y;
}

__global__ void k_gate(float* __restrict__ g) {
    int i = blockIdx.x * blockDim.x + threadIdx.x;
    if (i < NN) g[i] = 1.0f;
}

extern "C" void kernel_launch(void* const* d_in, const int* in_sizes, int n_in,
                              void* d_out, int out_size, void* d_ws, size_t ws_size,
                              hipStream_t stream) {
    const float* x = (const float*)d_in[0];
    const int* ei = (const int*)d_in[1];
    const float* wl[3] = {(const float*)d_in[3], (const float*)d_in[11], (const float*)d_in[19]};
    const float* bl[3] = {(const float*)d_in[4], (const float*)d_in[12], (const float*)d_in[20]};
    const float* wr[3] = {(const float*)d_in[5], (const float*)d_in[13], (const float*)d_in[21]};
    const float* br[3] = {(const float*)d_in[6], (const float*)d_in[14], (const float*)d_in[22]};
    const float* att[3] = {(const float*)d_in[7], (const float*)d_in[15], (const float*)d_in[23]};
    const float* bias[3] = {(const float*)d_in[8], (const float*)d_in[16], (const float*)d_in[24]};
    const float* bng[3] = {(const float*)d_in[9], (const float*)d_in[17], (const float*)d_in[25]};
    const float* bnb[3] = {(const float*)d_in[10], (const float*)d_in[18], (const float*)d_in[26]};

    // workspace layout (floats then ints), ~141 MB total
    float* fw = (float*)d_ws;
    float* xl = fw;                      // 10,240,000
    float* xr = xl + 10240000;           // 10,240,000
    float* h = xr + 10240000;            // 10,240,000
    float* zp = h + 10240000;            // 2,560,000
    float* lg = zp + 2560000;            // 1,360,000
    float* bsum = lg + 1360000;          // 512
    float* bsq = bsum + 512;             // 512
    float* bmu = bsq + 512;              // 512
    float* brs = bmu + 512;              // 512
    int* counts = (int*)(brs + 512);     // NN
    int* cursor = counts + NN;           // NN
    int* rstart = cursor + NN;           // NN+1
    int* csr = rstart + (NN + 1);        // ETOT
    size_t need = (size_t)(csr + ETOT - (int*)d_ws) * sizeof(int);
    if (ws_size < need) return;

    float* out = (float*)d_out;
    float* zout = out;                               // 20000 x 128
    float* aout[3] = {out + 2560000, out + 3920000, out + 5280000};  // 340000 x 4 each
    float* gout = out + 6640000;                     // 20000

    // CSR build (counts and cursor are adjacent -> one memset)
    hipMemsetAsync(counts, 0, 2 * NN * sizeof(int), stream);
    k_count<<<(ETOT + 255) / 256, 256, 0, stream>>>(ei, counts);
    k_scan<<<1, 1024, 0, stream>>>(counts, rstart);
    k_scatter<<<(ETOT + 255) / 256, 256, 0, stream>>>(ei, rstart, cursor, csr);

    const float* Ain = x;
    for (int l = 0; l < 3; ++l) {
        dim3 gg((NN + BM - 1) / BM, 512 / BN);
        k_gemm<<<gg, 256, 0, stream>>>(Ain, wl[l], bl[l], xl, NN);
        k_gemm<<<gg, 256, 0, stream>>>(Ain, wr[l], br[l], xr, NN);
        k_logits<<<ETOT / 4, 256, 0, stream>>>(xl, xr, att[l], ei, lg);
        k_softmax<<<NN / 4, 256, 0, stream>>>(lg, rstart, csr, aout[l]);
        int ncols = (l == 2) ? 128 : 512;
        float* dest = (l == 2) ? zp : h;
        k_agg<<<NN / 4, 256, 0, stream>>>(xl, aout[l], ei, rstart, csr, bias[l], dest, (l == 2) ? 1 : 0);
        hipMemsetAsync(bsum, 0, 1024 * sizeof(float), stream);
        k_bnstats<<<240, ncols, 0, stream>>>(dest, bsum, bsq, ncols);
        k_bnfin<<<1, ncols, 0, stream>>>(bsum, bsq, bmu, brs, ncols);
        int n4 = NN * ncols / 4;
        float* Y = (l == 2) ? zout : h;
        k_bnapply<<<(n4 + 255) / 256, 256, 0, stream>>>(dest, bng[l], bnb[l], bmu, brs, Y, ncols / 4 - 1, n4);
        Ain = h;
    }
    k_gate<<<(NN + 255) / 256, 256, 0, stream>>>(gout);
}

// Round 2
// 1032.074 us; speedup vs baseline: 2.0394x; 2.0394x over previous
//
#include <hip/hip_runtime.h>
#include <math.h>

#define NN 20000
#define EE 320000
#define ETOT 340000

typedef __attribute__((ext_vector_type(8))) short short8;
typedef __attribute__((ext_vector_type(4))) float f32x4;

__device__ __forceinline__ float lrelu(float x, float s) { return x > 0.f ? x : s * x; }
__device__ __forceinline__ float bf2f(ushort u) {
    union { uint i; float f; } c;
    c.i = ((uint)u) << 16;
    return c.f;
}
__device__ __forceinline__ ushort f2bf(float f) {
    uint u = __float_as_uint(f);
    uint r = (u + 0x7FFFu + ((u >> 16) & 1u)) >> 16;
    return (ushort)r;
}

// ---------------- CSR build ----------------
__global__ void k_count(const int* __restrict__ ei, int* __restrict__ counts) {
    int i = blockIdx.x * blockDim.x + threadIdx.x;
    if (i >= ETOT) return;
    int d = (i < EE) ? ei[EE + i] : (i - EE);
    atomicAdd(&counts[d], 1);
}

__global__ __launch_bounds__(1024) void k_scan(const int* __restrict__ counts, int* __restrict__ rstart) {
    __shared__ int sm[1024];
    int t = threadIdx.x;
    const int CH = 20;
    int base = t * CH;
    int loc[CH];
    int s = 0;
#pragma unroll
    for (int j = 0; j < CH; ++j) {
        int idx = base + j;
        int v = (idx < NN) ? counts[idx] : 0;
        loc[j] = s;
        s += v;
    }
    sm[t] = s;
    __syncthreads();
    for (int o = 1; o < 1024; o <<= 1) {
        int v = (t >= o) ? sm[t - o] : 0;
        __syncthreads();
        if (t >= o) sm[t] += v;
        __syncthreads();
    }
    int off = sm[t] - s;
#pragma unroll
    for (int j = 0; j < CH; ++j) {
        int idx = base + j;
        if (idx < NN) rstart[idx] = off + loc[j];
    }
    if (t == 1023) rstart[NN] = sm[1023];
}

__global__ void k_scatter(const int* __restrict__ ei, const int* __restrict__ rstart,
                          int* __restrict__ cursor, int* __restrict__ csr) {
    int i = blockIdx.x * blockDim.x + threadIdx.x;
    if (i >= ETOT) return;
    int d = (i < EE) ? ei[EE + i] : (i - EE);
    int pos = atomicAdd(&cursor[d], 1);
    csr[rstart[d] + pos] = i;
}

// ---------------- cast fp32 -> bf16 ----------------
__global__ void k_cast(const float* __restrict__ in, ushort* __restrict__ out, int n) {
    int i = (blockIdx.x * blockDim.x + threadIdx.x) * 4;
    if (i >= n) return;
    float4 v = *(const float4*)(in + i);
    ushort o0 = f2bf(v.x), o1 = f2bf(v.y), o2 = f2bf(v.z), o3 = f2bf(v.w);
    uint2 pk;
    pk.x = (uint)o0 | ((uint)o1 << 16);
    pk.y = (uint)o2 | ((uint)o3 << 16);
    *(uint2*)(out + i) = pk;
}

// ---------------- MFMA GEMM: C[M x 512](bf16) = A[M x 512](bf16) @ W[512 x 512]^T(bf16) + bias ----------------
// 128x128 tile, 256 threads = 4 waves (2x2), each wave 64x64 via 4x4 frags of 16x16x32.
__global__ __launch_bounds__(256) void k_gemm(const ushort* __restrict__ A, const ushort* __restrict__ W,
                                              const float* __restrict__ bias, ushort* __restrict__ C, int M) {
    // fragment-major LDS: [kslot][row][8 bf16] so a lane's b128 frag read is linear
    __shared__ ushort As[4][128][8];
    __shared__ ushort Bs[4][128][8];
    int tid = threadIdx.x;
    int wid = tid >> 6, lane = tid & 63;
    int wm = wid >> 1, wn = wid & 1;
    int bm = blockIdx.x * 128, bn = blockIdx.y * 128;
    int r = tid >> 1;            // staging row 0..127
    int kh = (tid & 1) * 2;      // staging slot base (0 or 2)
    int lrow = lane & 15, lslot = lane >> 4;
    f32x4 acc[4][4] = {};
    for (int k0 = 0; k0 < 512; k0 += 32) {
        int gr = bm + r;
        short8 a0 = {0, 0, 0, 0, 0, 0, 0, 0}, a1 = {0, 0, 0, 0, 0, 0, 0, 0};
        if (gr < M) {
            a0 = *(const short8*)(A + (size_t)gr * 512 + k0 + kh * 8);
            a1 = *(const short8*)(A + (size_t)gr * 512 + k0 + kh * 8 + 8);
        }
        short8 b0 = *(const short8*)(W + (size_t)(bn + r) * 512 + k0 + kh * 8);
        short8 b1 = *(const short8*)(W + (size_t)(bn + r) * 512 + k0 + kh * 8 + 8);
        *(short8*)&As[kh][r][0] = a0;
        *(short8*)&As[kh + 1][r][0] = a1;
        *(short8*)&Bs[kh][r][0] = b0;
        *(short8*)&Bs[kh + 1][r][0] = b1;
        __syncthreads();
        short8 af[4], bfr[4];
#pragma unroll
        for (int i = 0; i < 4; ++i) af[i] = *(const short8*)&As[lslot][wm * 64 + i * 16 + lrow][0];
#pragma unroll
        for (int j = 0; j < 4; ++j) bfr[j] = *(const short8*)&Bs[lslot][wn * 64 + j * 16 + lrow][0];
#pragma unroll
        for (int i = 0; i < 4; ++i)
#pragma unroll
            for (int j = 0; j < 4; ++j)
                acc[i][j] = __builtin_amdgcn_mfma_f32_16x16x32_bf16(af[i], bfr[j], acc[i][j], 0, 0, 0);
        __syncthreads();
    }
    // C/D layout: col = lane&15, row = (lane>>4)*4 + reg
#pragma unroll
    for (int i = 0; i < 4; ++i) {
#pragma unroll
        for (int j = 0; j < 4; ++j) {
            int gcol = bn + wn * 64 + j * 16 + lrow;
            float bv = bias[gcol];
            int growb = bm + wm * 64 + i * 16 + lslot * 4;
#pragma unroll
            for (int reg = 0; reg < 4; ++reg) {
                int grow = growb + reg;
                if (grow < M) C[(size_t)grow * 512 + gcol] = f2bf(acc[i][j][reg] + bv);
            }
        }
    }
}

// ---------------- edge logits: one wave per edge, bf16 rows ----------------
__global__ __launch_bounds__(256) void k_logits(const ushort* __restrict__ xl, const ushort* __restrict__ xr,
                                                const float* __restrict__ att, const int* __restrict__ ei,
                                                float* __restrict__ lg) {
    int gid = blockIdx.x * 4 + (threadIdx.x >> 6);
    int lane = threadIdx.x & 63;
    if (gid >= ETOT) return;
    int s = (gid < EE) ? ei[gid] : gid - EE;
    int d = (gid < EE) ? ei[EE + gid] : gid - EE;
    short8 a = *(const short8*)(xl + (size_t)s * 512 + lane * 8);
    short8 b = *(const short8*)(xr + (size_t)d * 512 + lane * 8);
    const float4* at = (const float4*)att + lane * 2;
    float4 w0 = at[0], w1 = at[1];
    float wv[8] = {w0.x, w0.y, w0.z, w0.w, w1.x, w1.y, w1.z, w1.w};
    float p = 0.f;
#pragma unroll
    for (int j = 0; j < 8; ++j) {
        float e = bf2f((ushort)a[j]) + bf2f((ushort)b[j]);
        p += lrelu(e, 0.2f) * wv[j];
    }
    p += __shfl_xor(p, 1);
    p += __shfl_xor(p, 2);
    p += __shfl_xor(p, 4);
    p += __shfl_xor(p, 8);
    if ((lane & 15) == 0) lg[(size_t)gid * 4 + (lane >> 4)] = p;
}

// ---------------- per-dst softmax ----------------
__global__ __launch_bounds__(256) void k_softmax(const float* __restrict__ lg, const int* __restrict__ rstart,
                                                 const int* __restrict__ csr, float* __restrict__ alpha) {
    int node = blockIdx.x * 4 + (threadIdx.x >> 6);
    int lane = threadIdx.x & 63;
    if (node >= NN) return;
    int s0 = rstart[node];
    int deg = rstart[node + 1] - s0;
    float m0 = -1e30f, m1 = -1e30f, m2 = -1e30f, m3 = -1e30f;
    for (int i = lane; i < deg; i += 64) {
        const float4 l = *(const float4*)(lg + (size_t)csr[s0 + i] * 4);
        m0 = fmaxf(m0, l.x); m1 = fmaxf(m1, l.y); m2 = fmaxf(m2, l.z); m3 = fmaxf(m3, l.w);
    }
#pragma unroll
    for (int o = 32; o >= 1; o >>= 1) {
        m0 = fmaxf(m0, __shfl_xor(m0, o));
        m1 = fmaxf(m1, __shfl_xor(m1, o));
        m2 = fmaxf(m2, __shfl_xor(m2, o));
        m3 = fmaxf(m3, __shfl_xor(m3, o));
    }
    float t0 = 0.f, t1 = 0.f, t2 = 0.f, t3 = 0.f;
    for (int i = lane; i < deg; i += 64) {
        const float4 l = *(const float4*)(lg + (size_t)csr[s0 + i] * 4);
        t0 += expf(l.x - m0); t1 += expf(l.y - m1); t2 += expf(l.z - m2); t3 += expf(l.w - m3);
    }
#pragma unroll
    for (int o = 32; o >= 1; o >>= 1) {
        t0 += __shfl_xor(t0, o); t1 += __shfl_xor(t1, o); t2 += __shfl_xor(t2, o); t3 += __shfl_xor(t3, o);
    }
    float r0 = 1.f / t0, r1 = 1.f / t1, r2 = 1.f / t2, r3 = 1.f / t3;
    for (int i = lane; i < deg; i += 64) {
        int e = csr[s0 + i];
        const float4 l = *(const float4*)(lg + (size_t)e * 4);
        float4 a;
        a.x = expf(l.x - m0) * r0;
        a.y = expf(l.y - m1) * r1;
        a.z = expf(l.z - m2) * r2;
        a.w = expf(l.w - m3) * r3;
        *(float4*)(alpha + (size_t)e * 4) = a;
    }
}

// ---------------- aggregate: one wave per node, bf16 gather ----------------
__global__ __launch_bounds__(256) void k_agg(const ushort* __restrict__ xl, const float* __restrict__ alpha,
                                             const int* __restrict__ ei, const int* __restrict__ rstart,
                                             const int* __restrict__ csr, const float* __restrict__ bias,
                                             float* __restrict__ out, int meanHeads) {
    int node = blockIdx.x * 4 + (threadIdx.x >> 6);
    int lane = threadIdx.x & 63;
    if (node >= NN) return;
    int s0 = rstart[node];
    int deg = rstart[node + 1] - s0;
    int hh = lane >> 4;
    float v[8] = {};
    for (int i = 0; i < deg; ++i) {
        int e = csr[s0 + i];
        int s = (e < EE) ? ei[e] : e - EE;
        float al = alpha[(size_t)e * 4 + hh];
        short8 row = *(const short8*)(xl + (size_t)s * 512 + lane * 8);
#pragma unroll
        for (int j = 0; j < 8; ++j) v[j] += al * bf2f((ushort)row[j]);
    }
    if (!meanHeads) {
        int c = lane * 8;
        float4 o0, o1;
        o0.x = v[0] + bias[c + 0]; o0.y = v[1] + bias[c + 1];
        o0.z = v[2] + bias[c + 2]; o0.w = v[3] + bias[c + 3];
        o1.x = v[4] + bias[c + 4]; o1.y = v[5] + bias[c + 5];
        o1.z = v[6] + bias[c + 6]; o1.w = v[7] + bias[c + 7];
        float4* o = (float4*)(out + (size_t)node * 512 + c);
        o[0] = o0;
        o[1] = o1;
    } else {
#pragma unroll
        for (int j = 0; j < 8; ++j) {
            v[j] += __shfl_xor(v[j], 16);
            v[j] += __shfl_xor(v[j], 32);
        }
        if (lane < 16) {
            int c = lane * 8;
#pragma unroll
            for (int j = 0; j < 8; ++j) out[(size_t)node * 128 + c + j] = 0.25f * v[j] + bias[c + j];
        }
    }
}

// ---------------- batch norm ----------------
__global__ void k_bnstats(const float* __restrict__ X, float* __restrict__ s, float* __restrict__ s2, int ncols) {
    int col = threadIdx.x;
    float a = 0.f, q = 0.f;
    for (int r = blockIdx.x; r < NN; r += gridDim.x) {
        float v = X[(size_t)r * ncols + col];
        a += v;
        q += v * v;
    }
    atomicAdd(&s[col], a);
    atomicAdd(&s2[col], q);
}

__global__ void k_bnfin(const float* __restrict__ s, const float* __restrict__ s2, float* __restrict__ mu,
                        float* __restrict__ rs, int ncols) {
    int c = threadIdx.x;
    if (c < ncols) {
        float m = s[c] * (1.f / NN);
        float v = s2[c] * (1.f / NN) - m * m;
        mu[c] = m;
        rs[c] = rsqrtf(v + 1e-5f);
    }
}

// writes bf16 (Yb != null) for next-layer GEMM input, or fp32 (Yf) for the final z
__global__ void k_bnapply(const float* __restrict__ X, const float* __restrict__ g, const float* __restrict__ b,
                          const float* __restrict__ mu, const float* __restrict__ rs, float* __restrict__ Yf,
                          ushort* __restrict__ Yb, int mask4, int n4) {
    int i = blockIdx.x * blockDim.x + threadIdx.x;
    if (i >= n4) return;
    int c = (i & mask4) << 2;
    float4 x = ((const float4*)X)[i];
    float4 G = *(const float4*)(g + c);
    float4 B = *(const float4*)(b + c);
    float4 M = *(const float4*)(mu + c);
    float4 R = *(const float4*)(rs + c);
    float4 y;
    y.x = lrelu(G.x * (x.x - M.x) * R.x + B.x, 0.01f);
    y.y = lrelu(G.y * (x.y - M.y) * R.y + B.y, 0.01f);
    y.z = lrelu(G.z * (x.z - M.z) * R.z + B.z, 0.01f);
    y.w = lrelu(G.w * (x.w - M.w) * R.w + B.w, 0.01f);
    if (Yb) {
        uint2 pk;
        pk.x = (uint)f2bf(y.x) | ((uint)f2bf(y.y) << 16);
        pk.y = (uint)f2bf(y.z) | ((uint)f2bf(y.w) << 16);
        *(uint2*)(Yb + (size_t)i * 4) = pk;
    } else {
        ((float4*)Yf)[i] = y;
    }
}

__global__ void k_gate(float* __restrict__ g) {
    int i = blockIdx.x * blockDim.x + threadIdx.x;
    if (i < NN) g[i] = 1.0f;
}

extern "C" void kernel_launch(void* const* d_in, const int* in_sizes, int n_in,
                              void* d_out, int out_size, void* d_ws, size_t ws_size,
                              hipStream_t stream) {
    const float* x = (const float*)d_in[0];
    const int* ei = (const int*)d_in[1];
    const float* wl[3] = {(const float*)d_in[3], (const float*)d_in[11], (const float*)d_in[19]};
    const float* bl[3] = {(const float*)d_in[4], (const float*)d_in[12], (const float*)d_in[20]};
    const float* wr[3] = {(const float*)d_in[5], (const float*)d_in[13], (const float*)d_in[21]};
    const float* br[3] = {(const float*)d_in[6], (const float*)d_in[14], (const float*)d_in[22]};
    const float* att[3] = {(const float*)d_in[7], (const float*)d_in[15], (const float*)d_in[23]};
    const float* bias[3] = {(const float*)d_in[8], (const float*)d_in[16], (const float*)d_in[24]};
    const float* bng[3] = {(const float*)d_in[9], (const float*)d_in[17], (const float*)d_in[25]};
    const float* bnb[3] = {(const float*)d_in[10], (const float*)d_in[18], (const float*)d_in[26]};

    // ---- workspace layout ----
    ushort* xl_bf = (ushort*)d_ws;            // 10,240,000
    ushort* xr_bf = xl_bf + 10240000;         // 10,240,000
    ushort* a_bf = xr_bf + 10240000;          // 10,240,000
    ushort* wlb = a_bf + 10240000;            // 262,144
    ushort* wrb = wlb + 262144;               // 262,144
    float* fp = (float*)(wrb + 262144);
    float* h = fp;                            // 10,240,000 (layer-1/2 agg out, fp32)
    float* zp = h + 10240000;                 // 2,560,000 (layer-3 agg out)
    float* lg = zp + 2560000;                 // 1,360,000
    float* bsum = lg + 1360000;               // 512
    float* bsq = bsum + 512;                  // 512
    float* bmu = bsq + 512;                   // 512
    float* brs = bmu + 512;                   // 512
    int* counts = (int*)(brs + 512);          // NN
    int* cursor = counts + NN;                // NN
    int* rstart = cursor + NN;                // NN+1
    int* csr = rstart + (NN + 1);             // ETOT
    size_t need = (size_t)((char*)(csr + ETOT) - (char*)d_ws);
    if (ws_size < need) return;

    float* out = (float*)d_out;
    float* zout = out;                                               // 20000 x 128
    float* aout[3] = {out + 2560000, out + 3920000, out + 5280000};  // 340000 x 4 each
    float* gout = out + 6640000;                                     // 20000

    // CSR build
    hipMemsetAsync(counts, 0, 2 * NN * sizeof(int), stream);
    k_count<<<(ETOT + 255) / 256, 256, 0, stream>>>(ei, counts);
    k_scan<<<1, 1024, 0, stream>>>(counts, rstart);
    k_scatter<<<(ETOT + 255) / 256, 256, 0, stream>>>(ei, rstart, cursor, csr);

    // cast x -> bf16 once
    k_cast<<<(NN * 512 / 4 + 255) / 256, 256, 0, stream>>>(x, a_bf, NN * 512);

    for (int l = 0; l < 3; ++l) {
        k_cast<<<(512 * 512 / 4 + 255) / 256, 256, 0, stream>>>(wl[l], wlb, 512 * 512);
        k_cast<<<(512 * 512 / 4 + 255) / 256, 256, 0, stream>>>(wr[l], wrb, 512 * 512);
        dim3 gg((NN + 127) / 128, 4);
        k_gemm<<<gg, 256, 0, stream>>>(a_bf, wlb, bl[l], xl_bf, NN);
        k_gemm<<<gg, 256, 0, stream>>>(a_bf, wrb, br[l], xr_bf, NN);
        k_logits<<<ETOT / 4, 256, 0, stream>>>(xl_bf, xr_bf, att[l], ei, lg);
        k_softmax<<<NN / 4, 256, 0, stream>>>(lg, rstart, csr, aout[l]);
        int ncols = (l == 2) ? 128 : 512;
        float* dest = (l == 2) ? zp : h;
        k_agg<<<NN / 4, 256, 0, stream>>>(xl_bf, aout[l], ei, rstart, csr, bias[l], dest, (l == 2) ? 1 : 0);
        hipMemsetAsync(bsum, 0, 1024 * sizeof(float), stream);
        k_bnstats<<<240, ncols, 0, stream>>>(dest, bsum, bsq, ncols);
        k_bnfin<<<1, ncols, 0, stream>>>(bsum, bsq, bmu, brs, ncols);
        int n4 = NN * ncols / 4;
        if (l < 2) {
            k_bnapply<<<(n4 + 255) / 256, 256, 0, stream>>>(dest, bng[l], bnb[l], bmu, brs, nullptr, a_bf,
                                                            ncols / 4 - 1, n4);
        } else {
            k_bnapply<<<(n4 + 255) / 256, 256, 0, stream>>>(dest, bng[l], bnb[l], bmu, brs, zout, nullptr,
                                                            ncols / 4 - 1, n4);
        }
    }
    k_gate<<<(NN + 255) / 256, 256, 0, stream>>>(gout);
}

// Round 3
// 732.758 us; speedup vs baseline: 2.8724x; 1.4085x over previous
//
#include <hip/hip_runtime.h>
#include <math.h>

#define NN 20000
#define EE 320000
#define ETOT 340000
#define MPAD 20096
#define DEGCAP 256

typedef __attribute__((ext_vector_type(8))) short short8;
typedef __attribute__((ext_vector_type(4))) float f32x4;

__device__ __forceinline__ float lrelu(float x, float s) { return fmaxf(x, s * x); }
__device__ __forceinline__ float bf2f(ushort u) {
    union { uint i; float f; } c;
    c.i = ((uint)u) << 16;
    return c.f;
}
__device__ __forceinline__ ushort f2bf(float f) {
    uint u = __float_as_uint(f);
    uint r = (u + 0x7FFFu + ((u >> 16) & 1u)) >> 16;
    return (ushort)r;
}
__device__ __forceinline__ void gload16(const ushort* g, ushort* l) {
    __builtin_amdgcn_global_load_lds((const __attribute__((address_space(1))) void*)g,
                                     (__attribute__((address_space(3))) void*)l, 16, 0, 0);
}

// ---------------- CSR build ----------------
__global__ void k_count(const int* __restrict__ ei, int* __restrict__ counts) {
    int i = blockIdx.x * blockDim.x + threadIdx.x;
    if (i >= ETOT) return;
    int d = (i < EE) ? ei[EE + i] : (i - EE);
    atomicAdd(&counts[d], 1);
}

__global__ __launch_bounds__(1024) void k_scan(const int* __restrict__ counts, int* __restrict__ rstart) {
    __shared__ int sm[1024];
    int t = threadIdx.x;
    const int CH = 20;
    int base = t * CH;
    int loc[CH];
    int s = 0;
#pragma unroll
    for (int j = 0; j < CH; ++j) {
        int idx = base + j;
        int v = (idx < NN) ? counts[idx] : 0;
        loc[j] = s;
        s += v;
    }
    sm[t] = s;
    __syncthreads();
    for (int o = 1; o < 1024; o <<= 1) {
        int v = (t >= o) ? sm[t - o] : 0;
        __syncthreads();
        if (t >= o) sm[t] += v;
        __syncthreads();
    }
    int off = sm[t] - s;
#pragma unroll
    for (int j = 0; j < CH; ++j) {
        int idx = base + j;
        if (idx < NN) rstart[idx] = off + loc[j];
    }
    if (t == 1023) rstart[NN] = sm[1023];
}

__global__ void k_scatter(const int* __restrict__ ei, const int* __restrict__ rstart,
                          int* __restrict__ cursor, int* __restrict__ csr) {
    int i = blockIdx.x * blockDim.x + threadIdx.x;
    if (i >= ETOT) return;
    int d = (i < EE) ? ei[EE + i] : (i - EE);
    int pos = atomicAdd(&cursor[d], 1);
    csr[rstart[d] + pos] = i;
}

// ---------------- casts ----------------
__global__ void k_cast(const float* __restrict__ in, ushort* __restrict__ out, int n) {
    int i = (blockIdx.x * blockDim.x + threadIdx.x) * 4;
    if (i >= n) return;
    float4 v = *(const float4*)(in + i);
    uint2 pk;
    pk.x = (uint)f2bf(v.x) | ((uint)f2bf(v.y) << 16);
    pk.y = (uint)f2bf(v.z) | ((uint)f2bf(v.w) << 16);
    *(uint2*)(out + i) = pk;
}

__global__ void k_castw(const float* __restrict__ w0, const float* __restrict__ w1, const float* __restrict__ w2,
                        const float* __restrict__ w3, const float* __restrict__ w4, const float* __restrict__ w5,
                        ushort* __restrict__ out) {
    int i = blockIdx.x * blockDim.x + threadIdx.x;  // quad index
    if (i >= 6 * 65536) return;
    int which = i >> 16;
    int off = (i & 65535) << 2;
    const float* src = which == 0 ? w0 : which == 1 ? w1 : which == 2 ? w2 : which == 3 ? w3 : which == 4 ? w4 : w5;
    float4 v = *(const float4*)(src + off);
    uint2 pk;
    pk.x = (uint)f2bf(v.x) | ((uint)f2bf(v.y) << 16);
    pk.y = (uint)f2bf(v.z) | ((uint)f2bf(v.w) << 16);
    *(uint2*)(out + which * 262144 + off) = pk;
}

// ---------------- MFMA GEMM with global_load_lds staging ----------------
// C[M x 512](bf16) = A[MPAD x 512](bf16) @ W[512 x 512]^T(bf16) + bias. A padded with zero rows.
__global__ __launch_bounds__(256) void k_gemm(const ushort* __restrict__ A, const ushort* __restrict__ W,
                                              const float* __restrict__ bias, ushort* __restrict__ C, int M) {
    __shared__ ushort As[4][128][8];  // [kslot][row][8] : flat 16B-chunk index = kslot*128+row
    __shared__ ushort Bs[4][128][8];
    int tid = threadIdx.x;
    int wid = tid >> 6, lane = tid & 63;
    int wm = wid >> 1, wn = wid & 1;
    int bm = blockIdx.x * 128, bn = blockIdx.y * 128;
    int lrow = lane & 15, lslot = lane >> 4;
    // staging: chunk f = kslot*128+row ; this thread handles f0=tid, f1=tid+256
    int f0 = tid, f1 = tid + 256;
    int r0 = f0 & 127, ks0 = f0 >> 7;
    int r1 = f1 & 127, ks1 = f1 >> 7;
    const ushort* ga0 = A + (size_t)(bm + r0) * 512 + ks0 * 8;
    const ushort* ga1 = A + (size_t)(bm + r1) * 512 + ks1 * 8;
    const ushort* gb0 = W + (size_t)(bn + r0) * 512 + ks0 * 8;
    const ushort* gb1 = W + (size_t)(bn + r1) * 512 + ks1 * 8;
    ushort* lA = &As[0][0][0];
    ushort* lB = &Bs[0][0][0];
    ushort* lA0 = lA + (size_t)(wid * 64) * 8;
    ushort* lA1 = lA + (size_t)(256 + wid * 64) * 8;
    ushort* lB0 = lB + (size_t)(wid * 64) * 8;
    ushort* lB1 = lB + (size_t)(256 + wid * 64) * 8;
    f32x4 acc[4][4] = {};
    for (int k0 = 0; k0 < 512; k0 += 32) {
        gload16(ga0 + k0, lA0);
        gload16(ga1 + k0, lA1);
        gload16(gb0 + k0, lB0);
        gload16(gb1 + k0, lB1);
        __syncthreads();
        short8 af[4], bfr[4];
#pragma unroll
        for (int i = 0; i < 4; ++i) af[i] = *(const short8*)&As[lslot][wm * 64 + i * 16 + lrow][0];
#pragma unroll
        for (int j = 0; j < 4; ++j) bfr[j] = *(const short8*)&Bs[lslot][wn * 64 + j * 16 + lrow][0];
#pragma unroll
        for (int i = 0; i < 4; ++i)
#pragma unroll
            for (int j = 0; j < 4; ++j)
                acc[i][j] = __builtin_amdgcn_mfma_f32_16x16x32_bf16(af[i], bfr[j], acc[i][j], 0, 0, 0);
        __syncthreads();
    }
#pragma unroll
    for (int i = 0; i < 4; ++i) {
#pragma unroll
        for (int j = 0; j < 4; ++j) {
            int gcol = bn + wn * 64 + j * 16 + lrow;
            float bv = bias[gcol];
            int growb = bm + wm * 64 + i * 16 + lslot * 4;
#pragma unroll
            for (int reg = 0; reg < 4; ++reg) {
                int grow = growb + reg;
                if (grow < M) C[(size_t)grow * 512 + gcol] = f2bf(acc[i][j][reg] + bv);
            }
        }
    }
}

// ---------------- fused logits + online-softmax + aggregation: one wave per dst node ----------------
__global__ __launch_bounds__(256) void k_fused(const ushort* __restrict__ xl, const ushort* __restrict__ xr,
                                               const float* __restrict__ att, const int* __restrict__ ei,
                                               const int* __restrict__ rstart, const int* __restrict__ csr,
                                               const float* __restrict__ bias, float* __restrict__ alpha,
                                               float* __restrict__ dest, int meanHeads) {
    __shared__ float slg[4][DEGCAP][4];
    __shared__ int ssrc[4][DEGCAP];
    int w = threadIdx.x >> 6, lane = threadIdx.x & 63;
    int node = blockIdx.x * 4 + w;
    int s0 = rstart[node];
    int deg = rstart[node + 1] - s0;
    int hh = lane >> 4;
    short8 xrv = *(const short8*)(xr + (size_t)node * 512 + lane * 8);
    const float4* at = (const float4*)att + lane * 2;
    float4 a0 = at[0], a1 = at[1];
    float attv[8] = {a0.x, a0.y, a0.z, a0.w, a1.x, a1.y, a1.z, a1.w};
    float xrf[8];
#pragma unroll
    for (int j = 0; j < 8; ++j) xrf[j] = bf2f((ushort)xrv[j]);
    // phase 1: resolve src ids into LDS
    for (int i = lane; i < deg; i += 64) {
        int e = csr[s0 + i];
        ssrc[w][i < DEGCAP ? i : 0] = (e < EE) ? ei[e] : e - EE;
    }
    // main pass (same-wave LDS RAW: compiler inserts lgkmcnt)
    float m = -1e30f, denom = 0.f;
    float acc[8] = {};
    int scur = ssrc[w][0];
    short8 row = *(const short8*)(xl + (size_t)scur * 512 + lane * 8);
    for (int i = 0; i < deg; ++i) {
        short8 rown = row;
        if (i + 1 < deg) {
            int sn = ssrc[w][(i + 1) < DEGCAP ? (i + 1) : 0];
            rown = *(const short8*)(xl + (size_t)sn * 512 + lane * 8);
        }
        float rf[8];
#pragma unroll
        for (int j = 0; j < 8; ++j) rf[j] = bf2f((ushort)row[j]);
        float p = 0.f;
#pragma unroll
        for (int j = 0; j < 8; ++j) {
            float e = rf[j] + xrf[j];
            p = fmaf(fmaxf(e, 0.2f * e), attv[j], p);
        }
        p += __shfl_xor(p, 1);
        p += __shfl_xor(p, 2);
        p += __shfl_xor(p, 4);
        p += __shfl_xor(p, 8);
        if ((lane & 15) == 0 && i < DEGCAP) slg[w][i][hh] = p;
        float mn = fmaxf(m, p);
        float sc = __expf(m - mn);
        float wg = __expf(p - mn);
        denom = denom * sc + wg;
#pragma unroll
        for (int j = 0; j < 8; ++j) acc[j] = acc[j] * sc + wg * rf[j];
        m = mn;
        row = rown;
    }
    float rd = 1.f / denom;
    // broadcast per-head m, rd
    float m0 = __shfl(m, 0), m1 = __shfl(m, 16), m2 = __shfl(m, 32), m3 = __shfl(m, 48);
    float r0 = __shfl(rd, 0), r1 = __shfl(rd, 16), r2 = __shfl(rd, 32), r3 = __shfl(rd, 48);
    int nal = deg < DEGCAP ? deg : DEGCAP;
    for (int i = lane; i < nal; i += 64) {
        int e = csr[s0 + i];
        float4 l = *(const float4*)&slg[w][i][0];
        float4 av;
        av.x = __expf(l.x - m0) * r0;
        av.y = __expf(l.y - m1) * r1;
        av.z = __expf(l.z - m2) * r2;
        av.w = __expf(l.w - m3) * r3;
        *(float4*)(alpha + (size_t)e * 4) = av;
    }
#pragma unroll
    for (int j = 0; j < 8; ++j) acc[j] *= rd;
    if (!meanHeads) {
        int c = lane * 8;
        float4 o0, o1;
        o0.x = acc[0] + bias[c + 0]; o0.y = acc[1] + bias[c + 1];
        o0.z = acc[2] + bias[c + 2]; o0.w = acc[3] + bias[c + 3];
        o1.x = acc[4] + bias[c + 4]; o1.y = acc[5] + bias[c + 5];
        o1.z = acc[6] + bias[c + 6]; o1.w = acc[7] + bias[c + 7];
        float4* o = (float4*)(dest + (size_t)node * 512 + c);
        o[0] = o0;
        o[1] = o1;
    } else {
#pragma unroll
        for (int j = 0; j < 8; ++j) {
            acc[j] += __shfl_xor(acc[j], 16);
            acc[j] += __shfl_xor(acc[j], 32);
        }
        if (lane < 16) {
            int c = lane * 8;
#pragma unroll
            for (int j = 0; j < 8; ++j) dest[(size_t)node * 128 + c + j] = 0.25f * acc[j] + bias[c + j];
        }
    }
}

// ---------------- batch norm ----------------
__global__ void k_bnstats(const float* __restrict__ X, float* __restrict__ s, float* __restrict__ s2, int ncols) {
    int col = threadIdx.x;
    float a = 0.f, q = 0.f;
    for (int r = blockIdx.x; r < NN; r += gridDim.x) {
        float v = X[(size_t)r * ncols + col];
        a += v;
        q += v * v;
    }
    atomicAdd(&s[col], a);
    atomicAdd(&s2[col], q);
}

__global__ void k_bnfin(const float* __restrict__ s, const float* __restrict__ s2, float* __restrict__ mu,
                        float* __restrict__ rs, int ncols) {
    int c = threadIdx.x;
    if (c < ncols) {
        float m = s[c] * (1.f / NN);
        float v = s2[c] * (1.f / NN) - m * m;
        mu[c] = m;
        rs[c] = rsqrtf(v + 1e-5f);
    }
}

__global__ void k_bnapply(const float* __restrict__ X, const float* __restrict__ g, const float* __restrict__ b,
                          const float* __restrict__ mu, const float* __restrict__ rs, float* __restrict__ Yf,
                          ushort* __restrict__ Yb, int mask4, int n4) {
    int i = blockIdx.x * blockDim.x + threadIdx.x;
    if (i >= n4) return;
    int c = (i & mask4) << 2;
    float4 x = ((const float4*)X)[i];
    float4 G = *(const float4*)(g + c);
    float4 B = *(const float4*)(b + c);
    float4 M = *(const float4*)(mu + c);
    float4 R = *(const float4*)(rs + c);
    float4 y;
    y.x = lrelu(G.x * (x.x - M.x) * R.x + B.x, 0.01f);
    y.y = lrelu(G.y * (x.y - M.y) * R.y + B.y, 0.01f);
    y.z = lrelu(G.z * (x.z - M.z) * R.z + B.z, 0.01f);
    y.w = lrelu(G.w * (x.w - M.w) * R.w + B.w, 0.01f);
    if (Yb) {
        uint2 pk;
        pk.x = (uint)f2bf(y.x) | ((uint)f2bf(y.y) << 16);
        pk.y = (uint)f2bf(y.z) | ((uint)f2bf(y.w) << 16);
        *(uint2*)(Yb + (size_t)i * 4) = pk;
    } else {
        ((float4*)Yf)[i] = y;
    }
}

__global__ void k_gate(float* __restrict__ g) {
    int i = blockIdx.x * blockDim.x + threadIdx.x;
    if (i < NN) g[i] = 1.0f;
}

extern "C" void kernel_launch(void* const* d_in, const int* in_sizes, int n_in,
                              void* d_out, int out_size, void* d_ws, size_t ws_size,
                              hipStream_t stream) {
    const float* x = (const float*)d_in[0];
    const int* ei = (const int*)d_in[1];
    const float* wl[3] = {(const float*)d_in[3], (const float*)d_in[11], (const float*)d_in[19]};
    const float* bl[3] = {(const float*)d_in[4], (const float*)d_in[12], (const float*)d_in[20]};
    const float* wr[3] = {(const float*)d_in[5], (const float*)d_in[13], (const float*)d_in[21]};
    const float* br[3] = {(const float*)d_in[6], (const float*)d_in[14], (const float*)d_in[22]};
    const float* att[3] = {(const float*)d_in[7], (const float*)d_in[15], (const float*)d_in[23]};
    const float* bias[3] = {(const float*)d_in[8], (const float*)d_in[16], (const float*)d_in[24]};
    const float* bng[3] = {(const float*)d_in[9], (const float*)d_in[17], (const float*)d_in[25]};
    const float* bnb[3] = {(const float*)d_in[10], (const float*)d_in[18], (const float*)d_in[26]};

    // ---- workspace layout ----
    ushort* a_bf = (ushort*)d_ws;             // MPAD*512 = 10,289,152 (padded GEMM input)
    ushort* xl_bf = a_bf + (size_t)MPAD * 512;  // 10,240,000
    ushort* xr_bf = xl_bf + 10240000;         // 10,240,000
    ushort* wbuf = xr_bf + 10240000;          // 6 * 262,144
    float* fp = (float*)(wbuf + 6 * 262144);
    float* h = fp;                            // 10,240,000 fp32 (layer-1/2 agg out)
    float* zp = h + 10240000;                 // 2,560,000 (layer-3 agg out)
    float* bsum = zp + 2560000;               // 512
    float* bsq = bsum + 512;                  // 512
    float* bmu = bsq + 512;                   // 512
    float* brs = bmu + 512;                   // 512
    int* counts = (int*)(brs + 512);          // NN
    int* cursor = counts + NN;                // NN
    int* rstart = cursor + NN;                // NN+1
    int* csr = rstart + (NN + 1);             // ETOT
    size_t need = (size_t)((char*)(csr + ETOT) - (char*)d_ws);
    if (ws_size < need) return;

    float* out = (float*)d_out;
    float* zout = out;                                               // 20000 x 128
    float* aout[3] = {out + 2560000, out + 3920000, out + 5280000};  // 340000 x 4 each
    float* gout = out + 6640000;                                     // 20000

    // CSR build
    hipMemsetAsync(counts, 0, 2 * NN * sizeof(int), stream);
    k_count<<<(ETOT + 255) / 256, 256, 0, stream>>>(ei, counts);
    k_scan<<<1, 1024, 0, stream>>>(counts, rstart);
    k_scatter<<<(ETOT + 255) / 256, 256, 0, stream>>>(ei, rstart, cursor, csr);

    // zero A pad rows (workspace is re-poisoned every launch), cast x, cast all weights
    hipMemsetAsync(a_bf + (size_t)NN * 512, 0, (size_t)(MPAD - NN) * 512 * sizeof(ushort), stream);
    k_cast<<<(NN * 512 / 4 + 255) / 256, 256, 0, stream>>>(x, a_bf, NN * 512);
    k_castw<<<(6 * 65536 + 255) / 256, 256, 0, stream>>>(wl[0], wr[0], wl[1], wr[1], wl[2], wr[2], wbuf);

    for (int l = 0; l < 3; ++l) {
        const ushort* wlb = wbuf + (size_t)(2 * l) * 262144;
        const ushort* wrb = wbuf + (size_t)(2 * l + 1) * 262144;
        dim3 gg(MPAD / 128, 4);
        k_gemm<<<gg, 256, 0, stream>>>(a_bf, wlb, bl[l], xl_bf, NN);
        k_gemm<<<gg, 256, 0, stream>>>(a_bf, wrb, br[l], xr_bf, NN);
        int ncols = (l == 2) ? 128 : 512;
        float* dest = (l == 2) ? zp : h;
        k_fused<<<NN / 4, 256, 0, stream>>>(xl_bf, xr_bf, att[l], ei, rstart, csr, bias[l], aout[l], dest,
                                            (l == 2) ? 1 : 0);
        hipMemsetAsync(bsum, 0, 1024 * sizeof(float), stream);
        k_bnstats<<<240, ncols, 0, stream>>>(dest, bsum, bsq, ncols);
        k_bnfin<<<1, ncols, 0, stream>>>(bsum, bsq, bmu, brs, ncols);
        int n4 = NN * ncols / 4;
        if (l < 2) {
            k_bnapply<<<(n4 + 255) / 256, 256, 0, stream>>>(dest, bng[l], bnb[l], bmu, brs, nullptr, a_bf,
                                                            ncols / 4 - 1, n4);
        } else {
            k_bnapply<<<(n4 + 255) / 256, 256, 0, stream>>>(dest, bng[l], bnb[l], bmu, brs, zout, nullptr,
                                                            ncols / 4 - 1, n4);
        }
    }
    k_gate<<<(NN + 255) / 256, 256, 0, stream>>>(gout);
}

// Round 4
// 677.283 us; speedup vs baseline: 3.1077x; 1.0819x over previous
//
#include <hip/hip_runtime.h>
#include <math.h>

#define NN 20000
#define EE 320000
#define ETOT 340000
#define DEGCAP 128

typedef __attribute__((ext_vector_type(8))) short short8;
typedef __attribute__((ext_vector_type(4))) float f32x4;

__device__ __forceinline__ float lrelu(float x, float s) { return fmaxf(x, s * x); }
__device__ __forceinline__ float bf2f(ushort u) {
    union { uint i; float f; } c;
    c.i = ((uint)u) << 16;
    return c.f;
}
__device__ __forceinline__ ushort f2bf(float f) {
    uint u = __float_as_uint(f);
    uint r = (u + 0x7FFFu + ((u >> 16) & 1u)) >> 16;
    return (ushort)r;
}
__device__ __forceinline__ void gload16(const ushort* g, ushort* l) {
    __builtin_amdgcn_global_load_lds((const __attribute__((address_space(1))) void*)g,
                                     (__attribute__((address_space(3))) void*)l, 16, 0, 0);
}

// ---------------- CSR build ----------------
__global__ void k_count(const int* __restrict__ ei, int* __restrict__ counts) {
    int i = blockIdx.x * blockDim.x + threadIdx.x;
    if (i >= ETOT) return;
    int d = (i < EE) ? ei[EE + i] : (i - EE);
    atomicAdd(&counts[d], 1);
}

__global__ __launch_bounds__(1024) void k_scan(const int* __restrict__ counts, int* __restrict__ rstart) {
    __shared__ int sm[1024];
    int t = threadIdx.x;
    const int CH = 20;
    int base = t * CH;
    int loc[CH];
    int s = 0;
#pragma unroll
    for (int j = 0; j < CH; ++j) {
        int idx = base + j;
        int v = (idx < NN) ? counts[idx] : 0;
        loc[j] = s;
        s += v;
    }
    sm[t] = s;
    __syncthreads();
    for (int o = 1; o < 1024; o <<= 1) {
        int v = (t >= o) ? sm[t - o] : 0;
        __syncthreads();
        if (t >= o) sm[t] += v;
        __syncthreads();
    }
    int off = sm[t] - s;
#pragma unroll
    for (int j = 0; j < CH; ++j) {
        int idx = base + j;
        if (idx < NN) rstart[idx] = off + loc[j];
    }
    if (t == 1023) rstart[NN] = sm[1023];
}

__global__ void k_scatter(const int* __restrict__ ei, const int* __restrict__ rstart,
                          int* __restrict__ cursor, int* __restrict__ csr) {
    int i = blockIdx.x * blockDim.x + threadIdx.x;
    if (i >= ETOT) return;
    int d = (i < EE) ? ei[EE + i] : (i - EE);
    int pos = atomicAdd(&cursor[d], 1);
    csr[rstart[d] + pos] = i;
}

// ---------------- casts ----------------
__global__ void k_cast(const float* __restrict__ in, ushort* __restrict__ out, int n) {
    int i = (blockIdx.x * blockDim.x + threadIdx.x) * 4;
    if (i >= n) return;
    float4 v = *(const float4*)(in + i);
    uint2 pk;
    pk.x = (uint)f2bf(v.x) | ((uint)f2bf(v.y) << 16);
    pk.y = (uint)f2bf(v.z) | ((uint)f2bf(v.w) << 16);
    *(uint2*)(out + i) = pk;
}

__global__ void k_castw(const float* __restrict__ w0, const float* __restrict__ w1, const float* __restrict__ w2,
                        const float* __restrict__ w3, const float* __restrict__ w4, const float* __restrict__ w5,
                        ushort* __restrict__ out) {
    int i = blockIdx.x * blockDim.x + threadIdx.x;  // quad index
    if (i >= 6 * 65536) return;
    int which = i >> 16;
    int off = (i & 65535) << 2;
    const float* src = which == 0 ? w0 : which == 1 ? w1 : which == 2 ? w2 : which == 3 ? w3 : which == 4 ? w4 : w5;
    float4 v = *(const float4*)(src + off);
    uint2 pk;
    pk.x = (uint)f2bf(v.x) | ((uint)f2bf(v.y) << 16);
    pk.y = (uint)f2bf(v.z) | ((uint)f2bf(v.w) << 16);
    *(uint2*)(out + which * 262144 + off) = pk;
}

// ---------------- merged MFMA GEMM: [xl|xr] = A[NN x 512] @ W[1024 x 512]^T + [bl|br] ----------------
// grid = 1256 blocks; XCD-swizzled so each XCD walks n-fastest over its own L range -> A panel L2-reuse.
__global__ __launch_bounds__(256) void k_gemm2(const ushort* __restrict__ A, const ushort* __restrict__ W,
                                               const float* __restrict__ bl, const float* __restrict__ br,
                                               ushort* __restrict__ XL, ushort* __restrict__ XR) {
    __shared__ ushort As[4][128][8];  // [kslot][row][8]
    __shared__ ushort Bs[4][128][8];
    int tid = threadIdx.x;
    int wid = tid >> 6, lane = tid & 63;
    int wm = wid >> 1, wn = wid & 1;
    // bijective XCD swizzle: 1256 % 8 == 0, 157 blocks per XCD, n-fastest within XCD
    int bid = blockIdx.x;
    int L = (bid & 7) * 157 + (bid >> 3);
    int mt = L >> 3, nt = L & 7;
    int bm = mt * 128, bn = nt * 128;
    const float* bias = (nt >= 4) ? br : bl;
    ushort* C = (nt >= 4) ? XR : XL;
    int cb = bn - ((nt >= 4) ? 512 : 0);
    int lrow = lane & 15, lslot = lane >> 4;
    int f0 = tid, f1 = tid + 256;
    int r0 = f0 & 127, ks0 = f0 >> 7;
    int r1 = f1 & 127, ks1 = f1 >> 7;
    int ar0 = bm + r0; if (ar0 >= NN) ar0 = NN - 1;   // clamp: rows >= NN never stored
    int ar1 = bm + r1; if (ar1 >= NN) ar1 = NN - 1;
    const ushort* ga0 = A + (size_t)ar0 * 512 + ks0 * 8;
    const ushort* ga1 = A + (size_t)ar1 * 512 + ks1 * 8;
    const ushort* gb0 = W + (size_t)(bn + r0) * 512 + ks0 * 8;
    const ushort* gb1 = W + (size_t)(bn + r1) * 512 + ks1 * 8;
    ushort* lA = &As[0][0][0];
    ushort* lB = &Bs[0][0][0];
    ushort* lA0 = lA + (size_t)(wid * 64) * 8;
    ushort* lA1 = lA + (size_t)(256 + wid * 64) * 8;
    ushort* lB0 = lB + (size_t)(wid * 64) * 8;
    ushort* lB1 = lB + (size_t)(256 + wid * 64) * 8;
    f32x4 acc[4][4] = {};
    for (int k0 = 0; k0 < 512; k0 += 32) {
        gload16(ga0 + k0, lA0);
        gload16(ga1 + k0, lA1);
        gload16(gb0 + k0, lB0);
        gload16(gb1 + k0, lB1);
        __syncthreads();
        short8 af[4], bfr[4];
#pragma unroll
        for (int i = 0; i < 4; ++i) af[i] = *(const short8*)&As[lslot][wm * 64 + i * 16 + lrow][0];
#pragma unroll
        for (int j = 0; j < 4; ++j) bfr[j] = *(const short8*)&Bs[lslot][wn * 64 + j * 16 + lrow][0];
#pragma unroll
        for (int i = 0; i < 4; ++i)
#pragma unroll
            for (int j = 0; j < 4; ++j)
                acc[i][j] = __builtin_amdgcn_mfma_f32_16x16x32_bf16(af[i], bfr[j], acc[i][j], 0, 0, 0);
        __syncthreads();
    }
#pragma unroll
    for (int i = 0; i < 4; ++i) {
#pragma unroll
        for (int j = 0; j < 4; ++j) {
            int gcol = cb + wn * 64 + j * 16 + lrow;
            float bv = bias[gcol];
            int growb = bm + wm * 64 + i * 16 + lslot * 4;
#pragma unroll
            for (int reg = 0; reg < 4; ++reg) {
                int grow = growb + reg;
                if (grow < NN) C[(size_t)grow * 512 + gcol] = f2bf(acc[i][j][reg] + bv);
            }
        }
    }
}

// ---------------- fused logits + online-softmax + aggregation: one wave per dst node ----------------
__global__ __launch_bounds__(256) void k_fused(const ushort* __restrict__ xl, const ushort* __restrict__ xr,
                                               const float* __restrict__ att, const int* __restrict__ ei,
                                               const int* __restrict__ rstart, const int* __restrict__ csr,
                                               const float* __restrict__ bias, float* __restrict__ alpha,
                                               ushort* __restrict__ dest, int meanHeads) {
    __shared__ float slg[4][DEGCAP][4];
    __shared__ int ssrc[4][DEGCAP];
    int w = threadIdx.x >> 6, lane = threadIdx.x & 63;
    int node = blockIdx.x * 4 + w;
    int s0 = rstart[node];
    int deg = rstart[node + 1] - s0;
    int hh = lane >> 4;
    short8 xrv = *(const short8*)(xr + (size_t)node * 512 + lane * 8);
    const float4* at = (const float4*)att + lane * 2;
    float4 a0 = at[0], a1 = at[1];
    float attv[8] = {a0.x, a0.y, a0.z, a0.w, a1.x, a1.y, a1.z, a1.w};
    float xrf[8];
#pragma unroll
    for (int j = 0; j < 8; ++j) xrf[j] = bf2f((ushort)xrv[j]);
    for (int i = lane; i < deg; i += 64) {
        int e = csr[s0 + i];
        ssrc[w][i < DEGCAP ? i : 0] = (e < EE) ? ei[e] : e - EE;
    }
    float m = -1e30f, denom = 0.f;
    float acc[8] = {};
    int scur = ssrc[w][0];
    short8 row = *(const short8*)(xl + (size_t)scur * 512 + lane * 8);
    for (int i = 0; i < deg; ++i) {
        short8 rown = row;
        if (i + 1 < deg) {
            int sn = ssrc[w][(i + 1) < DEGCAP ? (i + 1) : 0];
            rown = *(const short8*)(xl + (size_t)sn * 512 + lane * 8);
        }
        float rf[8];
#pragma unroll
        for (int j = 0; j < 8; ++j) rf[j] = bf2f((ushort)row[j]);
        float p = 0.f;
#pragma unroll
        for (int j = 0; j < 8; ++j) {
            float e = rf[j] + xrf[j];
            p = fmaf(fmaxf(e, 0.2f * e), attv[j], p);
        }
        p += __shfl_xor(p, 1);
        p += __shfl_xor(p, 2);
        p += __shfl_xor(p, 4);
        p += __shfl_xor(p, 8);
        if ((lane & 15) == 0 && i < DEGCAP) slg[w][i][hh] = p;
        if (p <= m) {  // common fast path: no rescale (uniform per 16-lane head group)
            float wg = __expf(p - m);
            denom += wg;
#pragma unroll
            for (int j = 0; j < 8; ++j) acc[j] = fmaf(wg, rf[j], acc[j]);
        } else {
            float sc = __expf(m - p);
            denom = fmaf(denom, sc, 1.f);
#pragma unroll
            for (int j = 0; j < 8; ++j) acc[j] = fmaf(acc[j], sc, rf[j]);
            m = p;
        }
        row = rown;
    }
    float rd = 1.f / denom;
    float m0 = __shfl(m, 0), m1 = __shfl(m, 16), m2 = __shfl(m, 32), m3 = __shfl(m, 48);
    float r0 = __shfl(rd, 0), r1 = __shfl(rd, 16), r2 = __shfl(rd, 32), r3 = __shfl(rd, 48);
    int nal = deg < DEGCAP ? deg : DEGCAP;
    for (int i = lane; i < nal; i += 64) {
        int e = csr[s0 + i];
        float4 l = *(const float4*)&slg[w][i][0];
        float4 av;
        av.x = __expf(l.x - m0) * r0;
        av.y = __expf(l.y - m1) * r1;
        av.z = __expf(l.z - m2) * r2;
        av.w = __expf(l.w - m3) * r3;
        *(float4*)(alpha + (size_t)e * 4) = av;
    }
#pragma unroll
    for (int j = 0; j < 8; ++j) acc[j] *= rd;
    if (!meanHeads) {
        int c = lane * 8;
        short8 o;
#pragma unroll
        for (int j = 0; j < 8; ++j) o[j] = (short)f2bf(acc[j] + bias[c + j]);
        *(short8*)(dest + (size_t)node * 512 + c) = o;
    } else {
#pragma unroll
        for (int j = 0; j < 8; ++j) {
            acc[j] += __shfl_xor(acc[j], 16);
            acc[j] += __shfl_xor(acc[j], 32);
        }
        if (lane < 16) {
            int c = lane * 8;
            short8 o;
#pragma unroll
            for (int j = 0; j < 8; ++j) o[j] = (short)f2bf(0.25f * acc[j] + bias[c + j]);
            *(short8*)(dest + (size_t)node * 128 + c) = o;
        }
    }
}

// ---------------- batch norm (bf16 input) ----------------
__global__ void k_bnstats(const ushort* __restrict__ X, float* __restrict__ s, float* __restrict__ s2, int npairs) {
    int t = threadIdx.x;
    if (t >= npairs) return;
    float a0 = 0.f, a1 = 0.f, q0 = 0.f, q1 = 0.f;
    for (int r = blockIdx.x; r < NN; r += gridDim.x) {
        uint p = ((const uint*)X)[r * npairs + t];
        float v0 = bf2f((ushort)(p & 0xffffu));
        float v1 = bf2f((ushort)(p >> 16));
        a0 += v0; q0 += v0 * v0;
        a1 += v1; q1 += v1 * v1;
    }
    atomicAdd(&s[2 * t], a0);
    atomicAdd(&s[2 * t + 1], a1);
    atomicAdd(&s2[2 * t], q0);
    atomicAdd(&s2[2 * t + 1], q1);
}

__global__ void k_bnfin(const float* __restrict__ s, const float* __restrict__ s2, float* __restrict__ mu,
                        float* __restrict__ rs, int ncols) {
    int c = threadIdx.x;
    if (c < ncols) {
        float m = s[c] * (1.f / NN);
        float v = s2[c] * (1.f / NN) - m * m;
        mu[c] = m;
        rs[c] = rsqrtf(v + 1e-5f);
    }
}

__global__ void k_bnapply(const ushort* __restrict__ X, const float* __restrict__ g, const float* __restrict__ b,
                          const float* __restrict__ mu, const float* __restrict__ rs, float* __restrict__ Yf,
                          ushort* __restrict__ Yb, int mask4, int n4) {
    int i = blockIdx.x * blockDim.x + threadIdx.x;
    if (i >= n4) return;
    int c = (i & mask4) << 2;
    uint2 p = ((const uint2*)X)[i];
    float x0 = bf2f((ushort)(p.x & 0xffffu)), x1 = bf2f((ushort)(p.x >> 16));
    float x2 = bf2f((ushort)(p.y & 0xffffu)), x3 = bf2f((ushort)(p.y >> 16));
    float4 G = *(const float4*)(g + c);
    float4 B = *(const float4*)(b + c);
    float4 M = *(const float4*)(mu + c);
    float4 R = *(const float4*)(rs + c);
    float4 y;
    y.x = lrelu(G.x * (x0 - M.x) * R.x + B.x, 0.01f);
    y.y = lrelu(G.y * (x1 - M.y) * R.y + B.y, 0.01f);
    y.z = lrelu(G.z * (x2 - M.z) * R.z + B.z, 0.01f);
    y.w = lrelu(G.w * (x3 - M.w) * R.w + B.w, 0.01f);
    if (Yb) {
        uint2 pk;
        pk.x = (uint)f2bf(y.x) | ((uint)f2bf(y.y) << 16);
        pk.y = (uint)f2bf(y.z) | ((uint)f2bf(y.w) << 16);
        *(uint2*)(Yb + (size_t)i * 4) = pk;
    } else {
        ((float4*)Yf)[i] = y;
    }
}

__global__ void k_gate(float* __restrict__ g) {
    int i = blockIdx.x * blockDim.x + threadIdx.x;
    if (i < NN) g[i] = 1.0f;
}

extern "C" void kernel_launch(void* const* d_in, const int* in_sizes, int n_in,
                              void* d_out, int out_size, void* d_ws, size_t ws_size,
                              hipStream_t stream) {
    const float* x = (const float*)d_in[0];
    const int* ei = (const int*)d_in[1];
    const float* wl[3] = {(const float*)d_in[3], (const float*)d_in[11], (const float*)d_in[19]};
    const float* bl[3] = {(const float*)d_in[4], (const float*)d_in[12], (const float*)d_in[20]};
    const float* wr[3] = {(const float*)d_in[5], (const float*)d_in[13], (const float*)d_in[21]};
    const float* br[3] = {(const float*)d_in[6], (const float*)d_in[14], (const float*)d_in[22]};
    const float* att[3] = {(const float*)d_in[7], (const float*)d_in[15], (const float*)d_in[23]};
    const float* bias[3] = {(const float*)d_in[8], (const float*)d_in[16], (const float*)d_in[24]};
    const float* bng[3] = {(const float*)d_in[9], (const float*)d_in[17], (const float*)d_in[25]};
    const float* bnb[3] = {(const float*)d_in[10], (const float*)d_in[18], (const float*)d_in[26]};

    // ---- workspace layout ----
    ushort* a_bf = (ushort*)d_ws;               // NN*512
    ushort* xl_bf = a_bf + (size_t)NN * 512;    // NN*512
    ushort* xr_bf = xl_bf + (size_t)NN * 512;   // NN*512
    ushort* h_bf = xr_bf + (size_t)NN * 512;    // NN*512 (pre-BN, bf16; also holds l=2's NN*128)
    ushort* wbuf = h_bf + (size_t)NN * 512;     // 6*262144
    float* fp = (float*)(wbuf + 6 * 262144);
    float* bsum = fp;                           // 512
    float* bsq = bsum + 512;                    // 512
    float* bmu = bsq + 512;                     // 512
    float* brs = bmu + 512;                     // 512
    int* counts = (int*)(brs + 512);            // NN
    int* cursor = counts + NN;                  // NN
    int* rstart = cursor + NN;                  // NN+1
    int* csr = rstart + (NN + 1);               // ETOT
    size_t need = (size_t)((char*)(csr + ETOT) - (char*)d_ws);
    if (ws_size < need) return;

    float* out = (float*)d_out;
    float* zout = out;                                               // 20000 x 128
    float* aout[3] = {out + 2560000, out + 3920000, out + 5280000};  // 340000 x 4 each
    float* gout = out + 6640000;                                     // 20000

    // CSR build
    hipMemsetAsync(counts, 0, 2 * NN * sizeof(int), stream);
    k_count<<<(ETOT + 255) / 256, 256, 0, stream>>>(ei, counts);
    k_scan<<<1, 1024, 0, stream>>>(counts, rstart);
    k_scatter<<<(ETOT + 255) / 256, 256, 0, stream>>>(ei, rstart, cursor, csr);

    k_cast<<<(NN * 512 / 4 + 255) / 256, 256, 0, stream>>>(x, a_bf, NN * 512);
    k_castw<<<(6 * 65536 + 255) / 256, 256, 0, stream>>>(wl[0], wr[0], wl[1], wr[1], wl[2], wr[2], wbuf);

    for (int l = 0; l < 3; ++l) {
        const ushort* wb = wbuf + (size_t)l * 524288;  // [Wl;Wr] rows
        k_gemm2<<<1256, 256, 0, stream>>>(a_bf, wb, bl[l], br[l], xl_bf, xr_bf);
        int ncols = (l == 2) ? 128 : 512;
        k_fused<<<NN / 4, 256, 0, stream>>>(xl_bf, xr_bf, att[l], ei, rstart, csr, bias[l], aout[l], h_bf,
                                            (l == 2) ? 1 : 0);
        hipMemsetAsync(bsum, 0, 1024 * sizeof(float), stream);
        k_bnstats<<<240, 256, 0, stream>>>(h_bf, bsum, bsq, ncols / 2);
        k_bnfin<<<1, ncols, 0, stream>>>(bsum, bsq, bmu, brs, ncols);
        int n4 = NN * ncols / 4;
        if (l < 2) {
            k_bnapply<<<(n4 + 255) / 256, 256, 0, stream>>>(h_bf, bng[l], bnb[l], bmu, brs, nullptr, a_bf,
                                                            ncols / 4 - 1, n4);
        } else {
            k_bnapply<<<(n4 + 255) / 256, 256, 0, stream>>>(h_bf, bng[l], bnb[l], bmu, brs, zout, nullptr,
                                                            ncols / 4 - 1, n4);
        }
    }
    k_gate<<<(NN + 255) / 256, 256, 0, stream>>>(gout);
}